// Round 4
// baseline (210.950 us; speedup 1.0000x reference)
//
#include <hip/hip_runtime.h>
#include <math.h>

#define H 64
#define W 64
#define C 256
#define O 256
#define CK 2304
#define NB 8
#define HWSZ 4096            // H*W
#define PX 32                // pixels per block (half row)

typedef __attribute__((ext_vector_type(8))) short short8;
typedef __attribute__((ext_vector_type(4))) float floatx4;
typedef __attribute__((ext_vector_type(4))) unsigned uintx4;

// swizzle giving uniform bank-group coverage in every 16-lane b128 phase
// for both the sampling-write map and the MFMA-read map
#define FSWZ(n) ((((n) & 3) << 1) | (((n) >> 2) & 1))

__device__ __forceinline__ float lo2f(unsigned u) {
  return __builtin_bit_cast(float, u << 16);
}
__device__ __forceinline__ float hi2f(unsigned u) {
  return __builtin_bit_cast(float, u & 0xffff0000u);
}
// pack two fp32 -> bf16 pair, round-half-up
__device__ __forceinline__ unsigned pk2bf(float v0, float v1) {
  unsigned a = __builtin_bit_cast(unsigned, v0);
  unsigned b = __builtin_bit_cast(unsigned, v1);
  return ((a + 0x8000u) >> 16) | ((b + 0x8000u) & 0xffff0000u);
}

// ---------------- prep_all: transpose + weight packs + BN, ONE launch -----
// region 0: bid <  1024 : transpose x NCHW fp32 -> NHWC bf16 (b = bid&7)
// region 1: bid < 1312 : prep main weight -> MFMA-A fragments (288 blocks)
// region 2: bid < 1348 : prep offset weight -> A fragments (36 blocks)
// region 3: bid == 1348: folded BN
__global__ __launch_bounds__(256) void prep_all(
    const float* __restrict__ x, const float* __restrict__ weight,
    const float* __restrict__ w_off, const float* __restrict__ bias,
    const float* __restrict__ gamma, const float* __restrict__ beta,
    const float* __restrict__ run_mean, const float* __restrict__ run_var,
    unsigned short* __restrict__ xt, unsigned short* __restrict__ wb,
    unsigned short* __restrict__ wob, float* __restrict__ invsh) {
  __shared__ unsigned tile[64 * 65];
  int bid = blockIdx.x;
  int tid = threadIdx.x;

  if (bid < 1024) {
    // ---- transpose: block = (b, y, cg-half of channels) ----
    int b = bid & 7;
    int t = bid >> 3;
    int y = t >> 1;
    int cg = t & 1;
    const float* xb = x + ((size_t)b * C + cg * 128) * HWSZ + y * W;
#pragma unroll
    for (int it = 0; it < 4; ++it) {
      int e = tid + 256 * it;              // (cp 0..63) x (xx4 0..15)
      int xx4 = e & 15;
      int cp = e >> 4;
      floatx4 f0 = *reinterpret_cast<const floatx4*>(
          xb + (size_t)(2 * cp) * HWSZ + xx4 * 4);
      floatx4 f1 = *reinterpret_cast<const floatx4*>(
          xb + (size_t)(2 * cp + 1) * HWSZ + xx4 * 4);
#pragma unroll
      for (int k = 0; k < 4; ++k)
        tile[cp * 65 + xx4 * 4 + k] = pk2bf(f0[k], f1[k]);
    }
    __syncthreads();
    unsigned short* xo = xt + ((size_t)(b * 64 + y) << 14) + cg * 128;
#pragma unroll
    for (int it = 0; it < 4; ++it) {
      int e = tid + 256 * it;
      int cq = e & 15;
      int xx = e >> 4;
      unsigned u0 = tile[(cq * 4 + 0) * 65 + xx];
      unsigned u1 = tile[(cq * 4 + 1) * 65 + xx];
      unsigned u2 = tile[(cq * 4 + 2) * 65 + xx];
      unsigned u3 = tile[(cq * 4 + 3) * 65 + xx];
      uint4 v = {u0, u1, u2, u3};
      *reinterpret_cast<uint4*>(xo + (xx << 8) + (cq << 3)) = v;
    }
  } else if (bid < 1312) {
    // ---- prep main weight: 8 elems/thread, one b128 store ----
    int d0 = ((bid - 1024) * 256 + tid) * 8;
    int lane = (d0 >> 3) & 63;
    int mt = (d0 >> 9) & 15;
    int ks = d0 >> 13;
    int o = mt * 16 + (lane & 15);
    int kn0 = ks * 32 + (lane >> 4) * 8;
    int tap = kn0 >> 8;
    int c0 = kn0 & 255;
    const float* wsrc = weight + o * CK + c0 * 9 + tap;
    unsigned pk[4];
#pragma unroll
    for (int p = 0; p < 4; ++p)
      pk[p] = pk2bf(wsrc[(2 * p) * 9], wsrc[(2 * p + 1) * 9]);
    uint4 v = {pk[0], pk[1], pk[2], pk[3]};
    *reinterpret_cast<uint4*>(wb + d0) = v;
  } else if (bid < 1348) {
    // ---- prep offset weight (M padded 27->32) ----
    int d0 = ((bid - 1312) * 256 + tid) * 8;
    int lane = (d0 >> 3) & 63;
    int mt = (d0 >> 9) & 1;
    int ks = d0 >> 10;
    int o = mt * 16 + (lane & 15);
    int kn0 = ks * 32 + (lane >> 4) * 8;
    int tap = kn0 >> 8;
    int c0 = kn0 & 255;
    uint4 v;
    if (o < 27) {
      const float* wsrc = w_off + o * CK + c0 * 9 + tap;
      unsigned pk[4];
#pragma unroll
      for (int p = 0; p < 4; ++p)
        pk[p] = pk2bf(wsrc[(2 * p) * 9], wsrc[(2 * p + 1) * 9]);
      v = (uint4){pk[0], pk[1], pk[2], pk[3]};
    } else {
      v = (uint4){0, 0, 0, 0};
    }
    *reinterpret_cast<uint4*>(wob + d0) = v;
  } else {
    // ---- folded BN ----
    int o = tid;
    float inv = gamma[o] * rsqrtf(run_var[o] + 1e-5f);
    invsh[o] = inv;
    invsh[O + o] = beta[o] + (bias[o] - run_mean[o]) * inv;
  }
}

// ---------------- Fused kernel: offset conv + deform sample + GEMM + BN ---
// grid (b, h, half), 512 threads (8 waves).  Block = half row: 32 px x 256
// out.  1024 blocks -> 4 blocks/CU (vs 2 before): latency hiding via TLP.
// Round-0 simple structure (single cols buffer, 2 barriers/tap) which the
// compiler schedules well; small acc (2x2 tiles, 16 VGPR) keeps us under the
// 64-VGPR cap so 8 waves/EU are resident.
__global__ __launch_bounds__(512, 4) void deform_mfma_kernel(
    const unsigned short* __restrict__ xt, const unsigned short* __restrict__ wob,
    const float* __restrict__ b_off, const unsigned short* __restrict__ wb,
    const float* __restrict__ invsh, float* __restrict__ out) {
  __shared__ short cols[PX * 256];       // 16 KB, FSWZ-swizzled
  __shared__ int sbase[9 * PX];
  __shared__ float s00[9 * PX], s01[9 * PX], s10[9 * PX], s11[9 * PX];
  // offset-conv result overlaid on cols (dead after phase A2)
  float* sm_om = reinterpret_cast<float*>(&cols[0]);      // 27*PX floats

  int tid = threadIdx.x;
  int lane = tid & 63;
  int wvid = tid >> 6;                   // 0..7
  int q = lane >> 4;
  int lm = lane & 15;
  int b = blockIdx.x;
  int h = blockIdx.y;
  int half = blockIdx.z;                 // 0/1: which 32-px half of the row
  const unsigned short* xtb = xt + ((size_t)b << 20);

  // ======== Phase A: offset conv, 4 active waves, wave = 1 mt x 1 nt(16px)
  if (wvid < 4) {
    int mt = wvid & 1;
    int nh = wvid >> 1;                  // px group of 16 within the half
    floatx4 a0 = (floatx4){0.f, 0.f, 0.f, 0.f};
    int pxn = nh * 16 + lm;              // local px 0..31
    int pxg = half * PX + pxn;           // global px 0..63
    for (int tap = 0; tap < 9; ++tap) {
      int yy = h - 1 + tap / 3;
      int xx = pxg - 1 + tap % 3;
      bool vv = (yy >= 0) && (yy < H) && (xx >= 0) && (xx < W);
      const unsigned short* bp =
          xtb + ((((yy & 63) << 6) + (xx & 63)) << 8) + q * 8;
#pragma unroll
      for (int s = 0; s < 8; ++s) {
        int ks = tap * 8 + s;
        short8 afrag = *reinterpret_cast<const short8*>(
            wob + (((ks * 2 + mt) * 64 + lane) << 3));
        short8 bfrag;
        if (vv)
          bfrag = *reinterpret_cast<const short8*>(bp + s * 32);
        else
          bfrag = (short8){0, 0, 0, 0, 0, 0, 0, 0};
        a0 = __builtin_amdgcn_mfma_f32_16x16x32_bf16(afrag, bfrag, a0, 0, 0, 0);
      }
    }
#pragma unroll
    for (int r = 0; r < 4; ++r) {
      int o = mt * 16 + q * 4 + r;
      if (o < 27) sm_om[o * PX + pxn] = a0[r] + b_off[o];
    }
  }
  __syncthreads();

  // ======== Phase A2: separable clamp-swap bilinear tables (9 taps x 32 px)
  if (tid < 9 * PX) {
    int n = tid & (PX - 1);
    int k = tid >> 5;
    float oy = sm_om[k * PX + n];
    float ox = sm_om[(9 + k) * PX + n];
    float mv = sm_om[(18 + k) * PX + n];
    float m = 1.0f / (1.0f + __expf(-mv));
    float py = (float)(h - 1 + k / 3) + oy;
    float px = (float)(half * PX + n - 1 + k % 3) + ox;
    float yf = floorf(py), xf = floorf(px);
    int y0 = (int)yf, x0 = (int)xf;
    float fy = py - yf, fx = px - xf;
    float r0, r1; int yl;
    if (y0 >= 0 && y0 <= H - 2)      { yl = y0;    r0 = 1.f - fy; r1 = fy;       }
    else if (y0 == -1)               { yl = 0;     r0 = fy;       r1 = 0.f;      }
    else if (y0 == H - 1)            { yl = H - 2; r0 = 0.f;      r1 = 1.f - fy; }
    else                             { yl = 0;     r0 = 0.f;      r1 = 0.f;      }
    float c0, c1; int xl;
    if (x0 >= 0 && x0 <= W - 2)      { xl = x0;    c0 = 1.f - fx; c1 = fx;       }
    else if (x0 == -1)               { xl = 0;     c0 = fx;       c1 = 0.f;      }
    else if (x0 == W - 1)            { xl = W - 2; c0 = 0.f;      c1 = 1.f - fx; }
    else                             { xl = 0;     c0 = 0.f;      c1 = 0.f;      }
    r0 *= m; r1 *= m;
    sbase[tid] = ((yl << 6) + xl) << 8;
    s00[tid] = r0 * c0; s01[tid] = r0 * c1;
    s10[tid] = r1 * c0; s11[tid] = r1 * c1;
  }
  __syncthreads();   // also protects sm_om (aliases cols) before tap-0 write

  // ======== Phase B: main deformable GEMM.  Wave = 2 m-tiles x 2 n-tiles
  floatx4 acc[2][2];                     // [m within pair][n-tile]
#pragma unroll
  for (int a = 0; a < 2; ++a)
#pragma unroll
    for (int u = 0; u < 2; ++u) acc[a][u] = (floatx4){0.f, 0.f, 0.f, 0.f};

  int sn = tid >> 4;        // pixel 0..31
  int scb = tid & 15;       // c-block low bits

  for (int tap = 0; tap < 9; ++tap) {
    if (tap) __syncthreads();
    // ---- sampling: 4 coalesced corner loads per c-block of 8 ----
    {
      int ei = tap * PX + sn;
      int base = sbase[ei];
      float w00 = s00[ei], w01 = s01[ei], w10 = s10[ei], w11 = s11[ei];
      const unsigned short* p = xtb + base;
#pragma unroll
      for (int i = 0; i < 2; ++i) {
        int cbw = (i << 4) | scb;
        int co = cbw << 3;
        uintx4 u00 = *reinterpret_cast<const uintx4*>(p + co);
        uintx4 u01 = *reinterpret_cast<const uintx4*>(p + 256 + co);
        uintx4 u10 = *reinterpret_cast<const uintx4*>(p + 16384 + co);
        uintx4 u11 = *reinterpret_cast<const uintx4*>(p + 16640 + co);
        uintx4 res;
#pragma unroll
        for (int jd = 0; jd < 4; ++jd) {
          float v0 = fmaf(w00, lo2f(u00[jd]),
                     fmaf(w01, lo2f(u01[jd]),
                     fmaf(w10, lo2f(u10[jd]), w11 * lo2f(u11[jd]))));
          float v1 = fmaf(w00, hi2f(u00[jd]),
                     fmaf(w01, hi2f(u01[jd]),
                     fmaf(w10, hi2f(u10[jd]), w11 * hi2f(u11[jd]))));
          res[jd] = pk2bf(v0, v1);
        }
        int pos = (cbw ^ FSWZ(sn)) & 31;
        *reinterpret_cast<uintx4*>(&cols[(sn << 8) + (pos << 3)]) = res;
      }
    }
    __syncthreads();

    // ---- MFMA: 8 k-steps, 2 m-tiles x 2 n-tiles per wave ----
    __builtin_amdgcn_s_setprio(1);
#pragma unroll
    for (int s = 0; s < 8; ++s) {
      int ks = tap * 8 + s;
      short8 afrag[2];
#pragma unroll
      for (int a = 0; a < 2; ++a)
        afrag[a] = *reinterpret_cast<const short8*>(
            wb + (((ks * 16 + wvid * 2 + a) * 64 + lane) << 3));
      short8 bfrag[2];
#pragma unroll
      for (int u = 0; u < 2; ++u) {
        int nn = u * 16 + lm;
        int pos = ((s * 4 + q) ^ FSWZ(nn)) & 31;
        bfrag[u] = *reinterpret_cast<const short8*>(&cols[(nn << 8) + (pos << 3)]);
      }
#pragma unroll
      for (int a = 0; a < 2; ++a)
#pragma unroll
        for (int u = 0; u < 2; ++u)
          acc[a][u] = __builtin_amdgcn_mfma_f32_16x16x32_bf16(
              afrag[a], bfrag[u], acc[a][u], 0, 0, 0);
    }
    __builtin_amdgcn_s_setprio(0);
  }

  // ---- epilogue: BN + ReLU + store ----
#pragma unroll
  for (int a = 0; a < 2; ++a) {
#pragma unroll
    for (int u = 0; u < 2; ++u) {
      int nn = u * 16 + lm;
#pragma unroll
      for (int r = 0; r < 4; ++r) {
        int o = (wvid * 2 + a) * 16 + q * 4 + r;
        float v = fmaf(acc[a][u][r], invsh[o], invsh[O + o]);
        out[((size_t)(b * O + o)) * HWSZ + h * W + half * PX + nn] =
            fmaxf(v, 0.0f);
      }
    }
  }
}

extern "C" void kernel_launch(void* const* d_in, const int* in_sizes, int n_in,
                              void* d_out, int out_size, void* d_ws, size_t ws_size,
                              hipStream_t stream) {
  const float* x        = (const float*)d_in[0];
  const float* w_off    = (const float*)d_in[1];
  const float* b_off    = (const float*)d_in[2];
  const float* weight   = (const float*)d_in[3];
  const float* bias     = (const float*)d_in[4];
  const float* gamma    = (const float*)d_in[5];
  const float* beta     = (const float*)d_in[6];
  const float* run_mean = (const float*)d_in[7];
  const float* run_var  = (const float*)d_in[8];
  float* out = (float*)d_out;

  // workspace layout (~18.1 MB)
  char* ws = (char*)d_ws;
  unsigned short* xt = (unsigned short*)ws;                    // 16777216 B
  unsigned short* wbf = (unsigned short*)(ws + 16777216);      // 1179648 B
  unsigned short* wob = (unsigned short*)(ws + 17956864);      // 147456 B
  float* invsh = (float*)(ws + 18104320);                      // 2048 B

  prep_all<<<1349, 256, 0, stream>>>(x, weight, w_off, bias, gamma, beta,
                                     run_mean, run_var, xt, wbf, wob, invsh);
  {
    dim3 grid(NB, H, 2);
    deform_mfma_kernel<<<grid, 512, 0, stream>>>(xt, wob, b_off, wbf, invsh, out);
  }
}

// Round 5
// 192.547 us; speedup vs baseline: 1.0956x; 1.0956x over previous
//
#include <hip/hip_runtime.h>
#include <math.h>

#define H 64
#define W 64
#define C 256
#define O 256
#define CK 2304
#define NB 8
#define HWSZ 4096            // H*W

typedef __attribute__((ext_vector_type(8))) short short8;
typedef __attribute__((ext_vector_type(4))) float floatx4;
typedef __attribute__((ext_vector_type(4))) unsigned uintx4;

// swizzle giving uniform bank-group coverage in every 16-lane b128 phase
// for both the sampling-write map and the MFMA-read map
#define FSWZ(n) ((((n) & 3) << 1) | (((n) >> 2) & 1))

__device__ __forceinline__ float lo2f(unsigned u) {
  return __builtin_bit_cast(float, u << 16);
}
__device__ __forceinline__ float hi2f(unsigned u) {
  return __builtin_bit_cast(float, u & 0xffff0000u);
}
// pack two fp32 -> bf16 pair, round-half-up
__device__ __forceinline__ unsigned pk2bf(float v0, float v1) {
  unsigned a = __builtin_bit_cast(unsigned, v0);
  unsigned b = __builtin_bit_cast(unsigned, v1);
  return ((a + 0x8000u) >> 16) | ((b + 0x8000u) & 0xffff0000u);
}

// ---------------- prep_x: transpose x NCHW fp32 -> NHWC bf16 --------------
// block = (b, 2-row group), 512 threads.  Reads 512B contiguous per channel
// (2 adjacent rows), writes one fully contiguous 32 KB span.  LDS 64 KB,
// XOR-swizzled (px ^ (cp&31)) instead of padding.
__global__ __launch_bounds__(512) void prep_x(
    const float* __restrict__ x, unsigned short* __restrict__ xt) {
  __shared__ unsigned tile[16384];       // [2][128][64] u32, 64 KB
  int bid = blockIdx.x;
  int tid = threadIdx.x;
  int b = bid >> 5;
  int yg = bid & 31;
  int y0 = yg * 2;

  // ---- phase 1: load ch-pair x 2 rows, pack bf16 pairs into LDS ----
#pragma unroll
  for (int j = 0; j < 4; ++j) {
    int e = tid + 512 * j;               // (cp 0..127) x (xx4 0..15)
    int xx4 = e & 15;
    int cp = e >> 4;
    const float* p0 = x + ((size_t)b * C + 2 * cp) * HWSZ + y0 * W + xx4 * 4;
    floatx4 f00 = *reinterpret_cast<const floatx4*>(p0);            // ch 2cp,   y0
    floatx4 f01 = *reinterpret_cast<const floatx4*>(p0 + W);        // ch 2cp,   y0+1
    floatx4 f10 = *reinterpret_cast<const floatx4*>(p0 + HWSZ);     // ch 2cp+1, y0
    floatx4 f11 = *reinterpret_cast<const floatx4*>(p0 + HWSZ + W); // ch 2cp+1, y0+1
    int sw = cp & 31;
#pragma unroll
    for (int k = 0; k < 4; ++k) {
      int px = xx4 * 4 + k;
      tile[cp * 64 + (px ^ sw)] = pk2bf(f00[k], f10[k]);
      tile[8192 + cp * 64 + (px ^ sw)] = pk2bf(f01[k], f11[k]);
    }
  }
  __syncthreads();

  // ---- phase 2: contiguous 32 KB store of 2 full NHWC rows ----
  unsigned short* xo = xt + ((size_t)(b * 64 + y0) << 14);
#pragma unroll
  for (int j = 0; j < 8; ++j) {
    int e = tid + 512 * j;               // (r 0..1) x (xx 0..63) x (cq 0..31)
    int cq = e & 31;
    int xx = (e >> 5) & 63;
    int r = e >> 11;
    unsigned u[4];
#pragma unroll
    for (int kk = 0; kk < 4; ++kk) {
      int cpv = cq * 4 + kk;
      u[kk] = tile[r * 8192 + cpv * 64 + (xx ^ (cpv & 31))];
    }
    uint4 v = {u[0], u[1], u[2], u[3]};
    *reinterpret_cast<uint4*>(xo + (r << 14) + (xx << 8) + (cq << 3)) = v;
  }
}

// ---------------- prep_wb: weight packs + folded BN -----------------------
// bid < 144 : prep main weight -> MFMA-A fragments
// bid < 162 : prep offset weight -> A fragments (M padded 27->32)
// bid ==162 : folded BN
__global__ __launch_bounds__(512) void prep_wb(
    const float* __restrict__ weight, const float* __restrict__ w_off,
    const float* __restrict__ bias, const float* __restrict__ gamma,
    const float* __restrict__ beta, const float* __restrict__ run_mean,
    const float* __restrict__ run_var, unsigned short* __restrict__ wb,
    unsigned short* __restrict__ wob, float* __restrict__ invsh) {
  int bid = blockIdx.x;
  int tid = threadIdx.x;

  if (bid < 144) {
    int idx = bid * 512 + tid;
    int d0 = idx * 8;
    int lane = idx & 63;
    int mt = (idx >> 6) & 15;
    int ks = idx >> 10;
    int o = mt * 16 + (lane & 15);
    int kn0 = ks * 32 + (lane >> 4) * 8;
    int tap = kn0 >> 8;
    int c0 = kn0 & 255;
    const float* wsrc = weight + o * CK + c0 * 9 + tap;
    unsigned pk[4];
#pragma unroll
    for (int p = 0; p < 4; ++p)
      pk[p] = pk2bf(wsrc[(2 * p) * 9], wsrc[(2 * p + 1) * 9]);
    uint4 v = {pk[0], pk[1], pk[2], pk[3]};
    *reinterpret_cast<uint4*>(wb + d0) = v;
  } else if (bid < 162) {
    int idx = (bid - 144) * 512 + tid;
    int d0 = idx * 8;
    int lane = idx & 63;
    int mt = (idx >> 6) & 1;
    int ks = idx >> 7;
    int o = mt * 16 + (lane & 15);
    int kn0 = ks * 32 + (lane >> 4) * 8;
    int tap = kn0 >> 8;
    int c0 = kn0 & 255;
    uint4 v;
    if (o < 27) {
      const float* wsrc = w_off + o * CK + c0 * 9 + tap;
      unsigned pk[4];
#pragma unroll
      for (int p = 0; p < 4; ++p)
        pk[p] = pk2bf(wsrc[(2 * p) * 9], wsrc[(2 * p + 1) * 9]);
      v = (uint4){pk[0], pk[1], pk[2], pk[3]};
    } else {
      v = (uint4){0, 0, 0, 0};
    }
    *reinterpret_cast<uint4*>(wob + d0) = v;
  } else {
    if (tid < 256) {
      int o = tid;
      float inv = gamma[o] * rsqrtf(run_var[o] + 1e-5f);
      invsh[o] = inv;
      invsh[O + o] = beta[o] + (bias[o] - run_mean[o]) * inv;
    }
  }
}

// ---------------- Fused kernel: offset conv + deform sample + GEMM + BN ---
// grid (b, h), 512 threads (8 waves).  Block = row h: 64 px x 256 out.
// (round-0 structure: best measured, 100 us)
__global__ __launch_bounds__(512, 4) void deform_mfma_kernel(
    const unsigned short* __restrict__ xt, const unsigned short* __restrict__ wob,
    const float* __restrict__ b_off, const unsigned short* __restrict__ wb,
    const float* __restrict__ invsh, float* __restrict__ out) {
  __shared__ short cols[64 * 256];       // 32 KB, FSWZ-swizzled
  __shared__ float sm_om[27 * 64];       // offset-conv result for this row
  __shared__ int sbase[576];
  __shared__ float s00[576], s01[576], s10[576], s11[576];

  int tid = threadIdx.x;
  int lane = tid & 63;
  int wvid = tid >> 6;                   // 0..7
  int q = lane >> 4;
  int lm = lane & 15;
  int b = blockIdx.x;
  int h = blockIdx.y;
  const unsigned short* xtb = xt + ((size_t)b << 20);

  // ======== Phase A: offset conv, 4 active waves, wave = 1 mt x 2 nt
  if (wvid < 4) {
    int mt = wvid & 1;
    int nh = wvid >> 1;                  // px quarter-pair
    floatx4 a0[2];
    a0[0] = (floatx4){0.f, 0.f, 0.f, 0.f};
    a0[1] = (floatx4){0.f, 0.f, 0.f, 0.f};
    int pxu[2];
    pxu[0] = (nh * 2 + 0) * 16 + lm;
    pxu[1] = (nh * 2 + 1) * 16 + lm;
    for (int tap = 0; tap < 9; ++tap) {
      int yy = h - 1 + tap / 3;
      bool vy = (yy >= 0) && (yy < H);
      const unsigned short* bp[2];
      bool vv[2];
#pragma unroll
      for (int u = 0; u < 2; ++u) {
        int xx = pxu[u] - 1 + tap % 3;
        vv[u] = vy && (xx >= 0) && (xx < W);
        bp[u] = xtb + ((((yy & 63) << 6) + (xx & 63)) << 8) + q * 8;
      }
#pragma unroll
      for (int s = 0; s < 8; ++s) {
        int ks = tap * 8 + s;
        short8 afrag = *reinterpret_cast<const short8*>(
            wob + (((ks * 2 + mt) * 64 + lane) << 3));
#pragma unroll
        for (int u = 0; u < 2; ++u) {
          short8 bfrag;
          if (vv[u])
            bfrag = *reinterpret_cast<const short8*>(bp[u] + s * 32);
          else
            bfrag = (short8){0, 0, 0, 0, 0, 0, 0, 0};
          a0[u] = __builtin_amdgcn_mfma_f32_16x16x32_bf16(afrag, bfrag, a0[u], 0, 0, 0);
        }
      }
    }
#pragma unroll
    for (int u = 0; u < 2; ++u)
#pragma unroll
      for (int r = 0; r < 4; ++r) {
        int o = mt * 16 + q * 4 + r;
        if (o < 27) sm_om[o * 64 + pxu[u]] = a0[u][r] + b_off[o];
      }
  }
  __syncthreads();

  // ======== Phase A2: separable clamp-swap bilinear tables (9 taps x 64 px)
  for (int e = tid; e < 576; e += 512) {
    int n = e & 63;
    int k = e >> 6;
    float oy = sm_om[k * 64 + n];
    float ox = sm_om[(9 + k) * 64 + n];
    float mv = sm_om[(18 + k) * 64 + n];
    float m = 1.0f / (1.0f + __expf(-mv));
    float py = (float)(h - 1 + k / 3) + oy;
    float px = (float)(n - 1 + k % 3) + ox;
    float yf = floorf(py), xf = floorf(px);
    int y0 = (int)yf, x0 = (int)xf;
    float fy = py - yf, fx = px - xf;
    float r0, r1; int yl;
    if (y0 >= 0 && y0 <= H - 2)      { yl = y0;    r0 = 1.f - fy; r1 = fy;       }
    else if (y0 == -1)               { yl = 0;     r0 = fy;       r1 = 0.f;      }
    else if (y0 == H - 1)            { yl = H - 2; r0 = 0.f;      r1 = 1.f - fy; }
    else                             { yl = 0;     r0 = 0.f;      r1 = 0.f;      }
    float c0, c1; int xl;
    if (x0 >= 0 && x0 <= W - 2)      { xl = x0;    c0 = 1.f - fx; c1 = fx;       }
    else if (x0 == -1)               { xl = 0;     c0 = fx;       c1 = 0.f;      }
    else if (x0 == W - 1)            { xl = W - 2; c0 = 0.f;      c1 = 1.f - fx; }
    else                             { xl = 0;     c0 = 0.f;      c1 = 0.f;      }
    r0 *= m; r1 *= m;
    sbase[e] = ((yl << 6) + xl) << 8;
    s00[e] = r0 * c0; s01[e] = r0 * c1;
    s10[e] = r1 * c0; s11[e] = r1 * c1;
  }
  __syncthreads();

  // ======== Phase B: main deformable GEMM.  Wave = 2 m-tiles x 4 n-tiles
  // (each (ks, m-tile) A-fragment loaded by exactly one wave)
  floatx4 acc[2][4];                     // [m within pair][n-tile]
#pragma unroll
  for (int a = 0; a < 2; ++a)
#pragma unroll
    for (int u = 0; u < 4; ++u) acc[a][u] = (floatx4){0.f, 0.f, 0.f, 0.f};

  int sn = tid >> 3;        // pixel 0..63
  int scb = tid & 7;        // c-block low bits

  for (int tap = 0; tap < 9; ++tap) {
    if (tap) __syncthreads();
    // ---- sampling: 4 coalesced corner loads per c-block of 8 ----
    {
      int ei = tap * 64 + sn;
      int base = sbase[ei];
      float w00 = s00[ei], w01 = s01[ei], w10 = s10[ei], w11 = s11[ei];
      const unsigned short* p = xtb + base;
#pragma unroll
      for (int i = 0; i < 4; ++i) {
        int cbw = (i << 3) | scb;
        int co = cbw << 3;
        uintx4 u00 = *reinterpret_cast<const uintx4*>(p + co);
        uintx4 u01 = *reinterpret_cast<const uintx4*>(p + 256 + co);
        uintx4 u10 = *reinterpret_cast<const uintx4*>(p + 16384 + co);
        uintx4 u11 = *reinterpret_cast<const uintx4*>(p + 16640 + co);
        uintx4 res;
#pragma unroll
        for (int jd = 0; jd < 4; ++jd) {
          float v0 = fmaf(w00, lo2f(u00[jd]),
                     fmaf(w01, lo2f(u01[jd]),
                     fmaf(w10, lo2f(u10[jd]), w11 * lo2f(u11[jd]))));
          float v1 = fmaf(w00, hi2f(u00[jd]),
                     fmaf(w01, hi2f(u01[jd]),
                     fmaf(w10, hi2f(u10[jd]), w11 * hi2f(u11[jd]))));
          res[jd] = pk2bf(v0, v1);
        }
        int pos = (cbw ^ FSWZ(sn)) & 31;
        *reinterpret_cast<uintx4*>(&cols[(sn << 8) + (pos << 3)]) = res;
      }
    }
    __syncthreads();

    // ---- MFMA: 8 k-steps, 2 m-tiles x 4 n-tiles per wave ----
#pragma unroll
    for (int s = 0; s < 8; ++s) {
      int ks = tap * 8 + s;
      short8 afrag[2];
#pragma unroll
      for (int a = 0; a < 2; ++a)
        afrag[a] = *reinterpret_cast<const short8*>(
            wb + (((ks * 16 + wvid * 2 + a) * 64 + lane) << 3));
      short8 bfrag[4];
#pragma unroll
      for (int u = 0; u < 4; ++u) {
        int nn = u * 16 + lm;
        int pos = ((s * 4 + q) ^ FSWZ(nn)) & 31;
        bfrag[u] = *reinterpret_cast<const short8*>(&cols[(nn << 8) + (pos << 3)]);
      }
#pragma unroll
      for (int a = 0; a < 2; ++a)
#pragma unroll
        for (int u = 0; u < 4; ++u)
          acc[a][u] = __builtin_amdgcn_mfma_f32_16x16x32_bf16(
              afrag[a], bfrag[u], acc[a][u], 0, 0, 0);
    }
  }

  // ---- epilogue: BN + ReLU + store ----
#pragma unroll
  for (int a = 0; a < 2; ++a) {
#pragma unroll
    for (int u = 0; u < 4; ++u) {
      int nn = u * 16 + lm;
#pragma unroll
      for (int r = 0; r < 4; ++r) {
        int o = (wvid * 2 + a) * 16 + q * 4 + r;
        float v = fmaf(acc[a][u][r], invsh[o], invsh[O + o]);
        out[((size_t)(b * O + o)) * HWSZ + h * W + nn] = fmaxf(v, 0.0f);
      }
    }
  }
}

extern "C" void kernel_launch(void* const* d_in, const int* in_sizes, int n_in,
                              void* d_out, int out_size, void* d_ws, size_t ws_size,
                              hipStream_t stream) {
  const float* x        = (const float*)d_in[0];
  const float* w_off    = (const float*)d_in[1];
  const float* b_off    = (const float*)d_in[2];
  const float* weight   = (const float*)d_in[3];
  const float* bias     = (const float*)d_in[4];
  const float* gamma    = (const float*)d_in[5];
  const float* beta     = (const float*)d_in[6];
  const float* run_mean = (const float*)d_in[7];
  const float* run_var  = (const float*)d_in[8];
  float* out = (float*)d_out;

  // workspace layout (~18.1 MB)
  char* ws = (char*)d_ws;
  unsigned short* xt = (unsigned short*)ws;                    // 16777216 B
  unsigned short* wbf = (unsigned short*)(ws + 16777216);      // 1179648 B
  unsigned short* wob = (unsigned short*)(ws + 17956864);      // 147456 B
  float* invsh = (float*)(ws + 18104320);                      // 2048 B

  prep_x<<<256, 512, 0, stream>>>(x, xt);
  prep_wb<<<163, 512, 0, stream>>>(weight, w_off, bias, gamma, beta,
                                   run_mean, run_var, wbf, wob, invsh);
  {
    dim3 grid(NB, H);
    deform_mfma_kernel<<<grid, 512, 0, stream>>>(xt, wob, b_off, wbf, invsh, out);
  }
}